// Round 1
// baseline (299.326 us; speedup 1.0000x reference)
//
#include <hip/hip_runtime.h>
#include <math.h>

#define NUM_POINTS 64
#define OUT_DIMS 128
#define BLOCK_THREADS 256
#define ELEMS_PER_BLOCK 256   // 32 iterations x 8 elements

__global__ __launch_bounds__(BLOCK_THREADS) void ce_kernel(
    const float* __restrict__ x,
    const float* __restrict__ emb,
    float* __restrict__ out) {
  // Stage embeddings (64 x 128 fp32 = 32 KB) in LDS once per block.
  __shared__ float s_emb[NUM_POINTS * OUT_DIMS];
  {
    float4* s4 = (float4*)s_emb;
    const float4* e4 = (const float4*)emb;
    const int t = threadIdx.x;
#pragma unroll
    for (int i = 0; i < (NUM_POINTS * OUT_DIMS / 4) / BLOCK_THREADS; ++i)
      s4[t + i * BLOCK_THREADS] = e4[t + i * BLOCK_THREADS];
  }
  __syncthreads();

  const int tid = threadIdx.x;
  const int lane_chunk = tid & 31;  // which float4 (of 32) in the 128 dims
  const int sub = tid >> 5;         // 0..7: element offset within an iteration
  const int base = blockIdx.x * ELEMS_PER_BLOCK;

#pragma unroll 1
  for (int it = 0; it < ELEMS_PER_BLOCK / 8; ++it) {
    const int e = base + it * 8 + sub;
    const float xv = x[e];
    // map [-1,1] -> [0, 64]
    const float xs = (xv + 1.0f) * 32.0f;
    // window support (xs-4, xs+4): the 8 candidates p0..p0+7 cover it.
    const int p0 = (int)floorf(xs) - 3;

    float w[8];
    float wsum = 0.0f;
#pragma unroll
    for (int j = 0; j < 8; ++j) {
      const int p = p0 + j;
      const float d = xs - (float)p;
      // cos(pi*d/8) == cos(2*pi * d/16); v_cos_f32 takes revolutions.
      const float c = __builtin_amdgcn_cosf(d * 0.0625f);
      float wv = c * c;
      // points outside the grid don't exist in the reference sum
      wv = (p >= 0 && p < NUM_POINTS) ? wv : 0.0f;
      w[j] = wv;
      wsum += wv;
    }
    const float inv = (wsum != 0.0f) ? __builtin_amdgcn_rcpf(wsum) : 0.0f;
#pragma unroll
    for (int j = 0; j < 8; ++j) w[j] *= inv;

    float4 acc = make_float4(0.f, 0.f, 0.f, 0.f);
#pragma unroll
    for (int j = 0; j < 8; ++j) {
      int p = p0 + j;
      p = (p < 0) ? 0 : ((p > NUM_POINTS - 1) ? NUM_POINTS - 1 : p);
      const float4 ev = ((const float4*)(s_emb + p * OUT_DIMS))[lane_chunk];
      acc.x = fmaf(w[j], ev.x, acc.x);
      acc.y = fmaf(w[j], ev.y, acc.y);
      acc.z = fmaf(w[j], ev.z, acc.z);
      acc.w = fmaf(w[j], ev.w, acc.w);
    }
    ((float4*)(out + (size_t)e * OUT_DIMS))[lane_chunk] = acc;
  }
}

extern "C" void kernel_launch(void* const* d_in, const int* in_sizes, int n_in,
                              void* d_out, int out_size, void* d_ws, size_t ws_size,
                              hipStream_t stream) {
  const float* x = (const float*)d_in[0];          // (64, 8192) fp32
  const float* emb = (const float*)d_in[1];        // (64, 128) fp32
  float* out = (float*)d_out;                      // (64, 8192, 128) fp32

  const int n = in_sizes[0];                       // 524288
  const int blocks = n / ELEMS_PER_BLOCK;          // 2048
  ce_kernel<<<blocks, BLOCK_THREADS, 0, stream>>>(x, emb, out);
}